// Round 6
// baseline (156.393 us; speedup 1.0000x reference)
//
#include <hip/hip_runtime.h>

// Per-batch confusion-matrix histogram:
//   gt  = trunc(segmap * 255.0f)   (f32 math, matches numpy/jax)
//   keep: gt != ignore (ignore = n_classes when use_dont_care else -1)
//   hist[b][pred][gt] += 1
//
// R1-R5 post-mortem: five structurally different LDS-atomic kernels all land
// at 43-48us; invariant = 1024 ds_add wave-ops/CU at ~100cyc each, immune to
// banking/replication/branch shape/memory source (warm replays identical).
// => DS ATOMIC path is near-serial per divergent lane (~1.5 cyc/lane).
// R6: zero atomics. Per-THREAD private u8 counters in LDS (128 x 364B =
// 46.6KB/block, 3 blocks/CU). Increment = ds_read_u8 + add + ds_write_b8 on
// the fast banked path. Max per (thread,bin) = 172 < 255: u8 safe even
// adversarially. Flush: u16 cross-thread byte-sums -> partials -> reduce.

#define NC2C    361
#define SLOTB   362    // bins incl. dummy (masked pixels -> bin 361)
#define RSTRIDE 364    // bytes per thread region; 91 words, gcd(91,32)=1
#define TPB     128
#define BPBn    12     // blocks per batch: 12*64 = 768 blocks = 3/CU (LDS-limited)

__global__ __launch_bounds__(256) void zero_out_kernel(int* __restrict__ out, int n) {
    int i = blockIdx.x * 256 + threadIdx.x;
    if (i < n) out[i] = 0;
}

// branch-free bin for one pixel: masked/out-of-range -> dummy bin nc2
__device__ __forceinline__ unsigned pix_bin(int pe, float se, int nc, int nc2,
                                            int ignore) {
    int g = (int)(se * 255.0f);
    unsigned b = (unsigned)(pe * nc + g);
    b = (g == ignore) ? (unsigned)nc2 : b;
    b = b < (unsigned)nc2 ? b : (unsigned)nc2;
    return b;
}

__device__ __forceinline__ void bump4(unsigned char* __restrict__ mine,
                                      int4 p, float4 s, int nc, int nc2, int ignore) {
    unsigned b0 = pix_bin(p.x, s.x, nc, nc2, ignore);
    unsigned b1 = pix_bin(p.y, s.y, nc, nc2, ignore);
    unsigned b2 = pix_bin(p.z, s.z, nc, nc2, ignore);
    unsigned b3 = pix_bin(p.w, s.w, nc, nc2, ignore);
    // private region: plain RMW, program order handles same-bin repeats
    mine[b0] = (unsigned char)(mine[b0] + 1);
    mine[b1] = (unsigned char)(mine[b1] + 1);
    mine[b2] = (unsigned char)(mine[b2] + 1);
    mine[b3] = (unsigned char)(mine[b3] + 1);
}

__global__ __launch_bounds__(TPB) void seg_hist_part(
    const int* __restrict__ pred,
    const float* __restrict__ seg,
    const int* __restrict__ ncls_p,
    const int* __restrict__ udc_p,
    int* __restrict__ partials,      // [B][BPBn][nc2]
    int npix_per_batch)
{
    __shared__ unsigned int hist32[(TPB * RSTRIDE) / 4];   // 46592 B
    unsigned char* h8 = (unsigned char*)hist32;

    const int nc = ncls_p[0];
    const int nc2 = nc * nc;
    const int ignore = udc_p[0] ? nc : -1;

    const int b = blockIdx.y;
    const int tid = threadIdx.x;

    for (int i = tid; i < (TPB * RSTRIDE) / 4; i += TPB) hist32[i] = 0;
    __syncthreads();

    unsigned char* mine = h8 + tid * RSTRIDE;

    const size_t base = (size_t)b * (size_t)npix_per_batch;
    const int4*   p4 = (const int4*)(pred + base);
    const float4* s4 = (const float4*)(seg + base);
    const int nvec = npix_per_batch >> 2;
    const int stride = BPBn * TPB;

    const int i0 = blockIdx.x * TPB + tid;
    const int niter = (i0 < nvec) ? (nvec - 1 - i0) / stride + 1 : 0;

    if (niter >= 2) {
        // depth-2 rotating prefetch: only 6 waves/CU, keep loads ahead of use
        int4   pa = p4[i0];          float4 sa = s4[i0];
        int4   pb = p4[i0 + stride]; float4 sb = s4[i0 + stride];
        int inext = i0 + 2 * stride;
        for (int t = 0; t < niter - 2; ++t, inext += stride) {
            int4   pc_ = p4[inext];
            float4 sc_ = s4[inext];
            bump4(mine, pa, sa, nc, nc2, ignore);
            pa = pb; sa = sb;
            pb = pc_; sb = sc_;
        }
        bump4(mine, pa, sa, nc, nc2, ignore);
        bump4(mine, pb, sb, nc, nc2, ignore);
    } else if (niter == 1) {
        bump4(mine, p4[i0], s4[i0], nc, nc2, ignore);
    }
    __syncthreads();

    // cross-thread flush: thread handles bin-pairs; u16 read = 2 adjacent bins
    int* pout = partials + ((size_t)b * BPBn + blockIdx.x) * (size_t)nc2;
    const int npair = (nc2 + 2) / 2;   // 181: pair 180 = (360, dummy)
    for (int pr = tid; pr < npair; pr += TPB) {
        int k0 = 2 * pr;
        int sum0 = 0, sum1 = 0;
        #pragma unroll 8
        for (int t = 0; t < TPB; ++t) {
            unsigned v = *(const unsigned short*)(h8 + t * RSTRIDE + k0);
            sum0 += (int)(v & 0xffu);
            sum1 += (int)(v >> 8);
        }
        pout[k0] = sum0;
        if (k0 + 1 < nc2) pout[k0 + 1] = sum1;
    }
}

__global__ __launch_bounds__(256) void reduce_part(
    const int* __restrict__ partials, int* __restrict__ out, int nc2)
{
    const int b = blockIdx.x;
    const int* p = partials + (size_t)b * BPBn * (size_t)nc2;
    for (int bin = threadIdx.x; bin < nc2; bin += 256) {
        int sum = 0;
        #pragma unroll
        for (int j = 0; j < BPBn; ++j) sum += p[(size_t)j * nc2 + bin];
        out[(size_t)b * nc2 + bin] = sum;
    }
}

// ---- fallback (ws too small): same private scheme, atomic flush to out ----
__global__ __launch_bounds__(TPB) void seg_hist_atomic(
    const int* __restrict__ pred, const float* __restrict__ seg,
    const int* __restrict__ ncls_p, const int* __restrict__ udc_p,
    int* __restrict__ out, int npix_per_batch)
{
    __shared__ unsigned int hist32[(TPB * RSTRIDE) / 4];
    unsigned char* h8 = (unsigned char*)hist32;
    const int nc = ncls_p[0];
    const int nc2 = nc * nc;
    const int ignore = udc_p[0] ? nc : -1;
    const int b = blockIdx.y;
    const int tid = threadIdx.x;
    for (int i = tid; i < (TPB * RSTRIDE) / 4; i += TPB) hist32[i] = 0;
    __syncthreads();
    unsigned char* mine = h8 + tid * RSTRIDE;
    const size_t base = (size_t)b * (size_t)npix_per_batch;
    const int4*   p4 = (const int4*)(pred + base);
    const float4* s4 = (const float4*)(seg + base);
    const int nvec = npix_per_batch >> 2;
    for (int i = blockIdx.x * TPB + tid; i < nvec; i += BPBn * TPB) {
        bump4(mine, p4[i], s4[i], nc, nc2, ignore);
    }
    __syncthreads();
    int* gout = out + (size_t)b * (size_t)nc2;
    const int npair = (nc2 + 2) / 2;
    for (int pr = tid; pr < npair; pr += TPB) {
        int k0 = 2 * pr;
        int sum0 = 0, sum1 = 0;
        for (int t = 0; t < TPB; ++t) {
            unsigned v = *(const unsigned short*)(h8 + t * RSTRIDE + k0);
            sum0 += (int)(v & 0xffu);
            sum1 += (int)(v >> 8);
        }
        if (sum0) atomicAdd(&gout[k0], sum0);
        if (k0 + 1 < nc2 && sum1) atomicAdd(&gout[k0 + 1], sum1);
    }
}

extern "C" void kernel_launch(void* const* d_in, const int* in_sizes, int n_in,
                              void* d_out, int out_size, void* d_ws, size_t ws_size,
                              hipStream_t stream) {
    const int*   pred = (const int*)d_in[0];
    const float* seg  = (const float*)d_in[1];
    const int*   ncp  = (const int*)d_in[2];
    const int*   udp  = (const int*)d_in[3];
    int* out = (int*)d_out;

    const int total_pix = in_sizes[0];         // B*H*W
    const int B = out_size / NC2C;             // 64 (nc=19 instance-fixed)
    const int npix_per_batch = total_pix / B;  // 262144
    const int nc2 = out_size / B;              // 361

    const size_t ws_needed = (size_t)B * BPBn * nc2 * sizeof(int);

    if (ws_size >= ws_needed) {
        int* partials = (int*)d_ws;
        dim3 grid(BPBn, B);
        seg_hist_part<<<grid, TPB, 0, stream>>>(pred, seg, ncp, udp, partials,
                                                npix_per_batch);
        reduce_part<<<B, 256, 0, stream>>>(partials, out, nc2);
    } else {
        int nblk = (out_size + 255) / 256;
        zero_out_kernel<<<nblk, 256, 0, stream>>>(out, out_size);
        dim3 grid(BPBn, B);
        seg_hist_atomic<<<grid, TPB, 0, stream>>>(pred, seg, ncp, udp, out,
                                                  npix_per_batch);
    }
}